// Round 7
// baseline (62.885 us; speedup 1.0000x reference)
//
#include <hip/hip_runtime.h>
#include <cmath>

#define NROWS 131072
#define D_IN 64
#define NMOD 64
#define HID 12
#define TPB 256
#define RPW 8
// waves = NROWS/RPW = 16384; blocks = 4096; target 8 waves/SIMD at <=64 VGPR

typedef __fp16 h2 __attribute__((ext_vector_type(2)));

__device__ __forceinline__ h2 pk_relu(h2 a) {
    asm("v_pk_max_f16 %0, %1, 0" : "=v"(a) : "v"(a));
    return a;
}
__device__ __forceinline__ float rl(float v, int sl) {
    return __int_as_float(__builtin_amdgcn_readlane(__float_as_int(v), sl));
}

// ---------------------------------------------------------------------------
// Single fused kernel.
// Preamble: every block redundantly computes the 129 top-2 routings (64+64+1)
// from the tiny emb tensors into LDS (~0.2 us, coalesced, L2-resident) --
// removes the separate routing kernel + graph dependency (fixed ~4-8 us).
// Main: lane = module; weights pair-packed f16 (hidden units j,j+1 share one
// h2 reg -> 6 regs/array, not 12 duplicated) to fit the <=64-VGPR tier ->
// 8 waves/SIMD for latency hiding. Layer-0 f16 (absmax ~4e-3 in R6); layer-1
// W2 accumulation f32. Phase-split keeps the two weight sets disjoint.
// ---------------------------------------------------------------------------
__global__ __launch_bounds__(TPB, 8) void moe_fused(
    const float* __restrict__ x,
    const float* __restrict__ emb0, const float* __restrict__ emb1,
    const float* __restrict__ emb_out,
    const float* __restrict__ W1_0, const float* __restrict__ b1_0,
    const float* __restrict__ W2_0, const float* __restrict__ b2_0,
    const float* __restrict__ W1_1, const float* __restrict__ b1_1,
    const float* __restrict__ W2_1, const float* __restrict__ b2_1,
    float* __restrict__ out) {

    __shared__ int rt[258];

    // ---- routing preamble: threads 0..128 each scan one module column ----
    {
        const int t = threadIdx.x;
        if (t < 129) {
            const float* e; int mm, M, base;
            if (t < 64)       { e = emb0;    mm = t;      M = 64; base = 0;   }
            else if (t < 128) { e = emb1;    mm = t - 64; M = 64; base = 128; }
            else              { e = emb_out; mm = 0;      M = 1;  base = 256; }

            int i1 = 0; float v1 = -INFINITY;
            for (int d = 0; d < 64; ++d) {
                float v = e[d * M + mm];
                if (v > v1) { v1 = v; i1 = d; }
            }
            int i2 = 0; float v2 = -INFINITY;
            for (int d = 0; d < 64; ++d) {
                if (d == i1) continue;
                float v = e[d * M + mm];
                if (v > v2) { v2 = v; i2 = d; }
            }
            if (t == 128) { rt[256] = i1; rt[257] = i2; }
            else          { rt[base + mm] = i1; rt[base + 64 + mm] = i2; }
        }
    }
    __syncthreads();

    const int lane = threadIdx.x & 63;
    const int wave = blockIdx.x * (TPB / 64) + (threadIdx.x >> 6);
    const int row0 = wave * RPW;
    const int m = lane;

    const int i1_0 = rt[m];
    const int i2_0 = rt[64 + m];
    const int i1_1 = rt[128 + m];
    const int i2_1 = rt[192 + m];
    const int io1 = __builtin_amdgcn_readfirstlane(rt[256]);
    const int io2 = __builtin_amdgcn_readfirstlane(rt[257]);

    // ---- x rows up front (coalesced 256B/row, 8 loads in flight) ----
    float xv[RPW];
#pragma unroll
    for (int r = 0; r < RPW; ++r)
        xv[r] = x[(size_t)(row0 + r) * D_IN + lane];

    // =================== PHASE A : layer 0 (pair-packed f16) ===================
    float y[RPW];
    {
        h2 w1a[6], w1b[6], b1p[6], w2p[6];
        const float4* Wp  = reinterpret_cast<const float4*>(W1_0 + m * 2 * HID);
        const float4* b1q = reinterpret_cast<const float4*>(b1_0 + m * HID);
        const float4* W2q = reinterpret_cast<const float4*>(W2_0 + m * HID);
#pragma unroll
        for (int q = 0; q < 3; ++q) {
            float4 f = Wp[q], g = Wp[3 + q], c = b1q[q], d = W2q[q];
            w1a[2*q]   = __builtin_amdgcn_cvt_pkrtz(f.x, f.y);
            w1a[2*q+1] = __builtin_amdgcn_cvt_pkrtz(f.z, f.w);
            w1b[2*q]   = __builtin_amdgcn_cvt_pkrtz(g.x, g.y);
            w1b[2*q+1] = __builtin_amdgcn_cvt_pkrtz(g.z, g.w);
            b1p[2*q]   = __builtin_amdgcn_cvt_pkrtz(c.x, c.y);
            b1p[2*q+1] = __builtin_amdgcn_cvt_pkrtz(c.z, c.w);
            w2p[2*q]   = __builtin_amdgcn_cvt_pkrtz(d.x, d.y);
            w2p[2*q+1] = __builtin_amdgcn_cvt_pkrtz(d.z, d.w);
        }
        const float b20 = b2_0[m];

#pragma unroll
        for (int r = 0; r < RPW; ++r) {
            const float v1f = __shfl(xv[r], i1_0);
            const float v2f = __shfl(xv[r], i2_0);
            const h2 v1 = __builtin_amdgcn_cvt_pkrtz(v1f, v1f);
            const h2 v2 = __builtin_amdgcn_cvt_pkrtz(v2f, v2f);
            h2 acc = {(__fp16)0.0f, (__fp16)0.0f};
#pragma unroll
            for (int jq = 0; jq < 6; ++jq) {
                h2 hd = v2 * w1b[jq] + b1p[jq];
                hd = v1 * w1a[jq] + hd;
                hd = pk_relu(hd);
                acc = hd * w2p[jq] + acc;
            }
            y[r] = b20 + ((float)acc[0] + (float)acc[1]);
        }
    }

    __builtin_amdgcn_sched_barrier(0);  // phase-A weight regs die here

    // ============ PHASE B : layer 1 (f16 hidden, f32 W2 accumulate) ============
    float vout = 0.0f;
    {
        h2 w1a[6], w1b[6], b1p[6];
        float w21[HID];
        const float4* Wp  = reinterpret_cast<const float4*>(W1_1 + m * 2 * HID);
        const float4* b1q = reinterpret_cast<const float4*>(b1_1 + m * HID);
        const float4* W2q = reinterpret_cast<const float4*>(W2_1 + m * HID);
#pragma unroll
        for (int q = 0; q < 3; ++q) {
            float4 f = Wp[q], g = Wp[3 + q], c = b1q[q], d = W2q[q];
            w1a[2*q]   = __builtin_amdgcn_cvt_pkrtz(f.x, f.y);
            w1a[2*q+1] = __builtin_amdgcn_cvt_pkrtz(f.z, f.w);
            w1b[2*q]   = __builtin_amdgcn_cvt_pkrtz(g.x, g.y);
            w1b[2*q+1] = __builtin_amdgcn_cvt_pkrtz(g.z, g.w);
            b1p[2*q]   = __builtin_amdgcn_cvt_pkrtz(c.x, c.y);
            b1p[2*q+1] = __builtin_amdgcn_cvt_pkrtz(c.z, c.w);
            w21[4*q]   = d.x; w21[4*q+1] = d.y;
            w21[4*q+2] = d.z; w21[4*q+3] = d.w;
        }
        const float b21 = b2_1[m];

#pragma unroll
        for (int r = 0; r < RPW; ++r) {
            const float g1f = __shfl(y[r], i1_1);
            const float g2f = __shfl(y[r], i2_1);
            const h2 g1 = __builtin_amdgcn_cvt_pkrtz(g1f, g1f);
            const h2 g2 = __builtin_amdgcn_cvt_pkrtz(g2f, g2f);
            float a0 = b21, a1 = 0.0f;
#pragma unroll
            for (int jq = 0; jq < 6; ++jq) {
                h2 hd = g2 * w1b[jq] + b1p[jq];
                hd = g1 * w1a[jq] + hd;
                hd = pk_relu(hd);
                a0 = fmaf((float)hd[0], w21[2*jq],     a0);
                a1 = fmaf((float)hd[1], w21[2*jq + 1], a1);
            }
            const float acc2 = a0 + a1;

            const float o1 = rl(acc2, io1);
            const float o2 = rl(acc2, io2);
            vout = (lane == 2 * r)     ? o1 : vout;
            vout = (lane == 2 * r + 1) ? o2 : vout;
        }
    }

    // sigmoid + coalesced 64B store per wave (lanes 0..15 = 8 rows x 2)
    if (lane < 2 * RPW) {
        const float s = 1.0f / (1.0f + __expf(-vout));
        out[(size_t)row0 * 2 + lane] = s;
    }
}

extern "C" void kernel_launch(void* const* d_in, const int* in_sizes, int n_in,
                              void* d_out, int out_size, void* d_ws, size_t ws_size,
                              hipStream_t stream) {
    const float* x       = (const float*)d_in[0];
    // d_in[1] = task_id; NUM_TASKS == 1 so always 0.
    const float* emb0    = (const float*)d_in[2];
    const float* emb1    = (const float*)d_in[3];
    const float* emb_out = (const float*)d_in[4];
    const float* W1_0    = (const float*)d_in[5];
    const float* b1_0    = (const float*)d_in[6];
    const float* W2_0    = (const float*)d_in[7];
    const float* b2_0    = (const float*)d_in[8];
    const float* W1_1    = (const float*)d_in[9];
    const float* b1_1    = (const float*)d_in[10];
    const float* W2_1    = (const float*)d_in[11];
    const float* b2_1    = (const float*)d_in[12];

    const int waves = NROWS / RPW;                 // 16384
    const int blocks = waves / (TPB / 64);         // 4096
    moe_fused<<<blocks, TPB, 0, stream>>>(
        x, emb0, emb1, emb_out,
        W1_0, b1_0, W2_0, b2_0, W1_1, b1_1, W2_1, b2_1,
        (float*)d_out);
}

// Round 8
// 14.041 us; speedup vs baseline: 4.4786x; 4.4786x over previous
//
#include <hip/hip_runtime.h>
#include <cmath>

#define NROWS 131072
#define TPB 256

// ---------------------------------------------------------------------------
// Key algebraic fact: the final output reads only columns io1, io2 of the
// layer-1 output (one-hot dot products). So only 2 layer-1 modules are
// observable; they consume 4 layer-0 modules, which consume 8 x-columns.
// Routing is data-independent of x and grid-uniform -> resolve the active
// sub-tree once per block (wave 0, ballot top-2), then each lane processes
// one full row with 6 tiny f32 MLPs and scalar (SGPR) weights.
// ---------------------------------------------------------------------------

// top-2 of v across the 64 lanes of wave 0; lowest-index tie-break = jax top_k
__device__ __forceinline__ void wave_top2(float v, int lane, int& i1, int& i2) {
    float m1 = v;
#pragma unroll
    for (int off = 32; off; off >>= 1) m1 = fmaxf(m1, __shfl_xor(m1, off));
    unsigned long long bm = __ballot(v == m1);
    i1 = __ffsll(bm) - 1;
    float vx = (lane == i1) ? -INFINITY : v;
    float m2 = vx;
#pragma unroll
    for (int off = 32; off; off >>= 1) m2 = fmaxf(m2, __shfl_xor(m2, off));
    bm = __ballot(vx == m2);
    i2 = __ffsll(bm) - 1;
}

__global__ __launch_bounds__(TPB) void moe_sparse(
    const float* __restrict__ x,
    const float* __restrict__ emb0, const float* __restrict__ emb1,
    const float* __restrict__ emb_out,
    const float* __restrict__ W1_0, const float* __restrict__ b1_0,
    const float* __restrict__ W2_0, const float* __restrict__ b2_0,
    const float* __restrict__ W1_1, const float* __restrict__ b1_1,
    const float* __restrict__ W2_1, const float* __restrict__ b2_1,
    float* __restrict__ out) {

    // rt[0]=io1 rt[1]=io2 ; rt[2..5] = the 4 layer-0 modules
    // (i1_1[io1], i2_1[io1], i1_1[io2], i2_1[io2]) ;
    // rt[6+2k], rt[7+2k] = x-columns (top-1, top-2) for layer-0 module k
    __shared__ int rt[14];

    if (threadIdx.x < 64) {
        const int lane = threadIdx.x;
        // stage 1: emb_out [64] -> io1, io2 (uniform value in every lane)
        int io1, io2;
        wave_top2(emb_out[lane], lane, io1, io2);
        // stage 2: emb1 columns io1, io2 (scan over layer-0 dim, stride 64)
        int a1, b1i, a2, b2i;
        wave_top2(emb1[lane * 64 + io1], lane, a1, b1i);
        wave_top2(emb1[lane * 64 + io2], lane, a2, b2i);
        const int mk[4] = {a1, b1i, a2, b2i};
        if (lane == 0) {
            rt[0] = io1; rt[1] = io2;
            rt[2] = a1; rt[3] = b1i; rt[4] = a2; rt[5] = b2i;
        }
        // stage 3: emb0 columns for the 4 active layer-0 modules
#pragma unroll
        for (int k = 0; k < 4; ++k) {
            int c1, c2;
            wave_top2(emb0[lane * 64 + mk[k]], lane, c1, c2);
            if (lane == 0) { rt[6 + 2 * k] = c1; rt[7 + 2 * k] = c2; }
        }
    }
    __syncthreads();

    // broadcast routing into SGPRs (forces scalar weight loads below)
    const int io1 = __builtin_amdgcn_readfirstlane(rt[0]);
    const int io2 = __builtin_amdgcn_readfirstlane(rt[1]);
    int m[4], ca[4], cb[4];
#pragma unroll
    for (int k = 0; k < 4; ++k) {
        m[k]  = __builtin_amdgcn_readfirstlane(rt[2 + k]);
        ca[k] = __builtin_amdgcn_readfirstlane(rt[6 + 2 * k]);
        cb[k] = __builtin_amdgcn_readfirstlane(rt[7 + 2 * k]);
    }

    const int row = blockIdx.x * TPB + threadIdx.x;
    const float* xr = x + (size_t)row * 64;

    // 8 feature gathers, all issued before first use (8 loads in flight)
    float va[4], vb[4];
#pragma unroll
    for (int k = 0; k < 4; ++k) { va[k] = xr[ca[k]]; vb[k] = xr[cb[k]]; }

    // layer 0: 4 active modules, f32, scalar weights
    float y[4];
#pragma unroll
    for (int k = 0; k < 4; ++k) {
        const float* w1 = W1_0 + m[k] * 24;
        const float* bb = b1_0 + m[k] * 12;
        const float* w2 = W2_0 + m[k] * 12;
        float acc = b2_0[m[k]];
#pragma unroll
        for (int j = 0; j < 12; ++j) {
            float h = fmaf(va[k], w1[j], fmaf(vb[k], w1[12 + j], bb[j]));
            acc = fmaf(fmaxf(h, 0.0f), w2[j], acc);
        }
        y[k] = acc;
    }

    // layer 1: module io1 consumes (y[0], y[1]); io2 consumes (y[2], y[3])
    float z[2];
    const int mo[2] = {io1, io2};
#pragma unroll
    for (int k = 0; k < 2; ++k) {
        const float* w1 = W1_1 + mo[k] * 24;
        const float* bb = b1_1 + mo[k] * 12;
        const float* w2 = W2_1 + mo[k] * 12;
        const float g1 = k ? y[2] : y[0];
        const float g2 = k ? y[3] : y[1];
        float acc = b2_1[mo[k]];
#pragma unroll
        for (int j = 0; j < 12; ++j) {
            float h = fmaf(g1, w1[j], fmaf(g2, w1[12 + j], bb[j]));
            acc = fmaf(fmaxf(h, 0.0f), w2[j], acc);
        }
        z[k] = acc;
    }

    float2 res;
    res.x = 1.0f / (1.0f + __expf(-z[0]));
    res.y = 1.0f / (1.0f + __expf(-z[1]));
    reinterpret_cast<float2*>(out)[row] = res;
}

extern "C" void kernel_launch(void* const* d_in, const int* in_sizes, int n_in,
                              void* d_out, int out_size, void* d_ws, size_t ws_size,
                              hipStream_t stream) {
    const float* x       = (const float*)d_in[0];
    // d_in[1] = task_id; NUM_TASKS == 1 so always 0.
    const float* emb0    = (const float*)d_in[2];
    const float* emb1    = (const float*)d_in[3];
    const float* emb_out = (const float*)d_in[4];
    const float* W1_0    = (const float*)d_in[5];
    const float* b1_0    = (const float*)d_in[6];
    const float* W2_0    = (const float*)d_in[7];
    const float* b2_0    = (const float*)d_in[8];
    const float* W1_1    = (const float*)d_in[9];
    const float* b1_1    = (const float*)d_in[10];
    const float* W2_1    = (const float*)d_in[11];
    const float* b2_1    = (const float*)d_in[12];

    moe_sparse<<<NROWS / TPB, TPB, 0, stream>>>(
        x, emb0, emb1, emb_out,
        W1_0, b1_0, W2_0, b2_0, W1_1, b1_1, W2_1, b2_1,
        (float*)d_out);
}